// Round 4
// baseline (280.948 us; speedup 1.0000x reference)
//
#include <hip/hip_runtime.h>
#include <math.h>

// LookupLanguageModel: n-gram backoff LM over a CSR-flattened trie.
// v-major: one thread owns one v for BG batches; the node's child-id and
// child-offset windows are staged once into LDS (int4) and reused per batch.
// R4: BG=8 (2000 waves -> ~8 waves/CU) and phase-split batch processing:
//   A) resolve level-1 per batch from LDS only (no global access),
//   B) issue ALL trigram probe/logps loads back-to-back (no branches between
//      them -> full memory-level parallelism within the wave),
//   C) pure-ALU finalize; rare sorted-window search fallback in a cold tail.

#define MAXN 8
#define BG   8
#define WI   37   // LDS row stride for ids window (odd => conflict-free)
#define WO   41   // LDS row stride for offsets window (odd)

struct PerB {
  int   ctx[MAXN];
  float bo[MAXN];
  float b1;
  int   hp;
};

__device__ __forceinline__ bool find_child(const int* __restrict__ offsets,
                                           const int* __restrict__ ids,
                                           int q, int t, int U, int P, int S,
                                           int* pos_out) {
  int start = offsets[q] + q;
  int end   = offsets[q + 1] + q + 1;
  int n = end - start;
  if (n > S) n = S;
  if (n <= 0) return false;
  int j = (t < n - 1) ? t : (n - 1);
  if (j < 0) j = 0;
  int x = ids[min(start + j, P - 1) - U];
  if (x == t) { *pos_out = start + j; return true; }
  if (x < t) return false;
  int lo = 0, hi = j - 1;
  while (lo < hi) {
    int mid = (lo + hi) >> 1;
    int xm = ids[min(start + mid, P - 1) - U];
    if (xm < t) lo = mid + 1; else hi = mid;
  }
  if (lo < j) {
    int xm = ids[min(start + lo, P - 1) - U];
    if (xm == t) { *pos_out = start + lo; return true; }
  }
  return false;
}

__global__ void lm_prep(const int* __restrict__ hist, const int* __restrict__ hidx,
                        const int* __restrict__ offsets, const int* __restrict__ ids,
                        const float* __restrict__ logbs,
                        const int* __restrict__ sos_p, const int* __restrict__ N_p,
                        const int* __restrict__ S_p,
                        PerB* __restrict__ pb, int V, int B, int L, int O, int P) {
  int b = blockIdx.x * blockDim.x + threadIdx.x;
  if (b >= B) return;
  int sos = *sos_p, N = *N_p, S = *S_p;
  if (N <= 1) return;
  int shift = (0 <= sos && sos < V) ? 0 : 1;
  int U = V + shift + 1 % N;
  int pad = N - 1;
  int hp = hidx[b] + pad;
  PerB o;
  o.hp = hp;
  for (int k = 0; k < N - 1; ++k) {
    int r = hp - (N - 1) + k;
    int tok = (r < pad) ? sos : hist[(r - pad) * B + b];
    if (shift && tok == sos) tok = V;
    o.ctx[k] = tok;
  }
  o.b1 = logbs[o.ctx[N - 2]];
  int desc = o.ctx[N - 2];
  bool found = true;
  for (int n = 1; n <= N - 2; ++n) {
    int t = o.ctx[(N - 1) - min(n + 1, N - 1)];
    if (found) {
      int pos;
      found = find_child(offsets, ids, desc, t, U, P, S, &pos);
      if (found) desc = pos;
    }
    o.bo[n] = found ? logbs[min(desc, O - 1)] : 0.0f;
  }
  pb[b] = o;
}

__device__ __forceinline__ float score_v(const int* __restrict__ offsets,
                                         const int* __restrict__ ids,
                                         const float* __restrict__ logps,
                                         const PerB* __restrict__ pbb,
                                         int v, float lp0,
                                         int N, int U, int O, int P, int S) {
  float last_lp = lp0;
  float last_bo = pbb->b1;
  int hp = pbb->hp;
  int desc = v;
  bool found = true;
  float cur_lp = lp0;
  for (int n = 1; n <= N - 1; ++n) {
    int t = pbb->ctx[(N - 1) - n];
    if (found) {
      int pos;
      found = find_child(offsets, ids, desc, t, U, P, S, &pos);
      if (found) { desc = pos; cur_lp = logps[desc]; }
    }
    float cur_bo = (n == N - 1) ? 0.0f : pbb->bo[n];
    bool clobber = isfinite(cur_lp) && found;
    float newlp = clobber ? cur_lp : (last_lp + cur_bo + last_bo);
    last_bo = clobber ? cur_bo : 0.0f;
    if (hp >= n) last_lp = newlp;
  }
  return last_lp;
}

__global__ void __launch_bounds__(64)
lm_main2(const int* __restrict__ offsets, const int* __restrict__ ids,
         const float* __restrict__ logps,
         const int* __restrict__ sos_p, const int* __restrict__ N_p,
         const int* __restrict__ S_p,
         const PerB* __restrict__ pb, float* __restrict__ out,
         int V, int B, int O, int P) {
  __shared__ int   s_t1[BG], s_t0[BG], s_hp[BG];
  __shared__ float s_bo1[BG], s_b1[BG];
  __shared__ int   ids_w[64 * WI];
  __shared__ int   off_w[64 * WO];

  const int tid = threadIdx.x;
  const int v   = blockIdx.x * 64 + tid;
  const int b0  = blockIdx.y * BG;
  const int N = *N_p, S = *S_p, sos = *sos_p;
  const int Nc = (N > 0) ? N : 1;
  const int shift = (0 <= sos && sos < V) ? 0 : 1;
  const int U = V + shift + 1 % Nc;

  const bool fast = (N == 3) && (S == 32);

  if (!fast) {
    if (v < V) {
      float lp0 = logps[v];
      if (N <= 1) {
        for (int i = 0; i < BG; ++i) {
          int b = b0 + i;
          if (b < B) out[(size_t)b * V + v] = lp0;
        }
      } else {
        for (int i = 0; i < BG; ++i) {
          int b = b0 + i;
          if (b < B)
            out[(size_t)b * V + v] = score_v(offsets, ids, logps, pb + b, v,
                                             lp0, N, U, O, P, S);
        }
      }
    }
    return;
  }

  if (tid < BG) {
    int b = b0 + tid;
    if (b < B) {
      const PerB* q = pb + b;
      s_t1[tid]  = q->ctx[1];
      s_t0[tid]  = q->ctx[0];
      s_bo1[tid] = q->bo[1];
      s_b1[tid]  = q->b1;
      s_hp[tid]  = q->hp;
    }
  }
  __syncthreads();
  if (v >= V) return;

  const int idsN = P - U;
  float lp0 = logps[v];
  int ov  = offsets[v];
  int ov1 = offsets[v + 1];
  int start1 = ov + v;
  int n1 = ov1 + 1 - ov;
  if (n1 > 32) n1 = 32;

  int* myids = ids_w + tid * WI;
  int* myoff = off_w + tid * WO;
  int aidx0 = start1 - U;
  int sh_i = 0, sh_o = 0;
  bool vec_ok = (start1 >= 0) && (aidx0 >= 0) &&
                (((aidx0 & ~3) + 36) <= idsN) &&
                (((start1 & ~3) + 40) <= O);
  if (vec_ok) {
    int ab = aidx0 & ~3;
    sh_i = aidx0 - ab;
    const int4* ip = (const int4*)(ids + ab);
#pragma unroll
    for (int k = 0; k < 9; ++k) {
      int4 t = ip[k];
      myids[4 * k + 0] = t.x; myids[4 * k + 1] = t.y;
      myids[4 * k + 2] = t.z; myids[4 * k + 3] = t.w;
    }
    int ob = start1 & ~3;
    sh_o = start1 - ob;
    const int4* op = (const int4*)(offsets + ob);
#pragma unroll
    for (int k = 0; k < 10; ++k) {
      int4 t = op[k];
      myoff[4 * k + 0] = t.x; myoff[4 * k + 1] = t.y;
      myoff[4 * k + 2] = t.z; myoff[4 * k + 3] = t.w;
    }
  } else {
    for (int j = 0; j < 36; ++j) {
      int ii = min(start1 + j, P - 1) - U;
      ii = max(0, min(ii, idsN - 1));
      myids[j] = ids[ii];
    }
    for (int j = 0; j < 40; ++j) {
      int oo = max(0, min(start1 + j, O - 1));
      myoff[j] = offsets[oo];
    }
  }
  // each thread reads only its own LDS rows -> no barrier needed

  const int nb = min(BG, B - b0);

  // ---- phase A: LDS-only level-1 resolution + trigram candidate addresses
  int j1v[BG];
  int cc1[BG];
  int cc2[BG];
  unsigned f1m = 0, l2m = 0;
#pragma unroll
  for (int i = 0; i < BG; ++i) {
    if (i >= nb) { j1v[i] = 0; cc1[i] = v; cc2[i] = v; continue; }
    int t1 = s_t1[i];
    bool found = false;
    int j1 = 0;
    if (n1 > 0) {
      int jj = (t1 < n1 - 1) ? t1 : (n1 - 1);
      if (jj < 0) jj = 0;
      int x = myids[sh_i + jj];
      if (x == t1) { found = true; j1 = jj; }
      else if (x > t1) {
        int lo = 0, hi = jj - 1;
        while (lo < hi) {
          int mid = (lo + hi) >> 1;
          if (myids[sh_i + mid] < t1) lo = mid + 1; else hi = mid;
        }
        if (lo < jj && myids[sh_i + lo] == t1) { found = true; j1 = lo; }
      }
    }
    int c1 = start1 + j1;
    j1v[i] = j1;
    int a1 = min(c1, P - 1);
    cc1[i] = a1;
    // level-2 candidate (from LDS offsets window)
    int t0 = s_t0[i];
    int o1 = myoff[sh_o + j1];
    int o2 = myoff[sh_o + j1 + 1];
    int start2 = o1 + c1;
    int n2 = o2 + 1 - o1;
    if (n2 > 32) n2 = 32;
    bool l2ok = found && (n2 > 0);
    int jj2 = (t0 < n2 - 1) ? t0 : (n2 - 1);
    if (jj2 < 0) jj2 = 0;
    int c2 = min(start2 + jj2, P - 1);
    cc2[i] = l2ok ? c2 : a1;   // aliases an already-fetched line when skipped
    f1m |= (found ? 1u : 0u) << i;
    l2m |= (l2ok ? 1u : 0u) << i;
  }

  // ---- phase B: batched global loads, no branches in between
  float lp1v[BG];
  int   x2v[BG];
  float sp2v[BG];
#pragma unroll
  for (int i = 0; i < BG; ++i) lp1v[i] = logps[cc1[i]];
#pragma unroll
  for (int i = 0; i < BG; ++i) {
    int ii = cc2[i] - U;
    ii = max(0, min(ii, idsN - 1));
    x2v[i] = ids[ii];
  }
#pragma unroll
  for (int i = 0; i < BG; ++i) sp2v[i] = logps[cc2[i]];

  // ---- phase C: finalize (pure ALU; global search fallback is cold)
#pragma unroll
  for (int i = 0; i < BG; ++i) {
    if (i >= nb) continue;
    bool found = (f1m >> i) & 1u;
    bool l2ok  = (l2m >> i) & 1u;
    int   hp = s_hp[i];
    float bo1 = s_bo1[i];
    float last_bo = s_b1[i];
    float last_lp = lp0;

    float lp1 = found ? lp1v[i] : lp0;
    bool clob = found && isfinite(lp1);
    float nl = clob ? lp1 : (last_lp + bo1 + last_bo);
    last_bo = clob ? bo1 : 0.0f;
    if (hp >= 1) last_lp = nl;

    bool f2 = false;
    float lp2 = 0.0f;
    if (l2ok) {
      int t0 = s_t0[i];
      int x2 = x2v[i];
      if (x2 == t0) { f2 = true; lp2 = sp2v[i]; }
      else if (x2 > t0) {
        // cold: sorted-window binary search in global ids
        int j1 = j1v[i];
        int c1 = start1 + j1;
        int o1 = myoff[sh_o + j1];
        int o2 = myoff[sh_o + j1 + 1];
        int start2 = o1 + c1;
        int n2 = o2 + 1 - o1;
        if (n2 > 32) n2 = 32;
        int jj2 = (t0 < n2 - 1) ? t0 : (n2 - 1);
        if (jj2 < 0) jj2 = 0;
        int lo = 0, hi = jj2 - 1;
        while (lo < hi) {
          int mid = (lo + hi) >> 1;
          int im = max(0, min(min(start2 + mid, P - 1) - U, idsN - 1));
          if (ids[im] < t0) lo = mid + 1; else hi = mid;
        }
        if (lo < jj2) {
          int il = max(0, min(min(start2 + lo, P - 1) - U, idsN - 1));
          if (ids[il] == t0) { f2 = true; lp2 = logps[min(start2 + lo, P - 1)]; }
        }
      }
    }
    bool clob2 = f2 && isfinite(lp2);
    float nl2 = clob2 ? lp2 : (last_lp + last_bo);
    if (hp >= 2) last_lp = nl2;

    out[(size_t)(b0 + i) * V + v] = last_lp;
  }
}

extern "C" void kernel_launch(void* const* d_in, const int* in_sizes, int n_in,
                              void* d_out, int out_size, void* d_ws, size_t ws_size,
                              hipStream_t stream) {
  const int*   hist    = (const int*)d_in[0];
  const int*   hidx    = (const int*)d_in[1];
  const int*   offsets = (const int*)d_in[2];
  const int*   ids     = (const int*)d_in[3];
  const float* logps   = (const float*)d_in[4];
  const float* logbs   = (const float*)d_in[5];
  const int*   sos_p   = (const int*)d_in[6];
  const int*   N_p     = (const int*)d_in[8];
  const int*   S_p     = (const int*)d_in[10];

  int B = in_sizes[1];
  int L = in_sizes[0] / B;
  int O = in_sizes[2];
  int P = in_sizes[4];
  int V = out_size / B;
  float* out = (float*)d_out;
  PerB* pb = (PerB*)d_ws;

  lm_prep<<<dim3((B + 63) / 64), dim3(64), 0, stream>>>(
      hist, hidx, offsets, ids, logbs, sos_p, N_p, S_p, pb, V, B, L, O, P);

  dim3 grid((V + 63) / 64, (B + BG - 1) / BG);
  lm_main2<<<grid, dim3(64), 0, stream>>>(
      offsets, ids, logps, sos_p, N_p, S_p, pb, out, V, B, O, P);
}

// Round 5
// 275.452 us; speedup vs baseline: 1.0200x; 1.0200x over previous
//
#include <hip/hip_runtime.h>
#include <math.h>

// LookupLanguageModel: n-gram backoff LM over a CSR-flattened trie.
// v-major: one thread owns one v for BG batches; the node's child-id and
// child-offset windows are staged once into LDS (int4) and reused per batch.
// R5: BG=16 (R3's best config) + phase-split batched gathers (MLP) +
// non-temporal trigram gathers / output stores (use-once traffic bypasses
// L2 replacement, preserving the reused bigram windows in L2).

#define MAXN 8
#define BG   16
#define WI   37   // LDS row stride for ids window (odd => conflict-free)
#define WO   41   // LDS row stride for offsets window (odd)

struct PerB {
  int   ctx[MAXN];
  float bo[MAXN];
  float b1;
  int   hp;
};

__device__ __forceinline__ bool find_child(const int* __restrict__ offsets,
                                           const int* __restrict__ ids,
                                           int q, int t, int U, int P, int S,
                                           int* pos_out) {
  int start = offsets[q] + q;
  int end   = offsets[q + 1] + q + 1;
  int n = end - start;
  if (n > S) n = S;
  if (n <= 0) return false;
  int j = (t < n - 1) ? t : (n - 1);
  if (j < 0) j = 0;
  int x = ids[min(start + j, P - 1) - U];
  if (x == t) { *pos_out = start + j; return true; }
  if (x < t) return false;
  int lo = 0, hi = j - 1;
  while (lo < hi) {
    int mid = (lo + hi) >> 1;
    int xm = ids[min(start + mid, P - 1) - U];
    if (xm < t) lo = mid + 1; else hi = mid;
  }
  if (lo < j) {
    int xm = ids[min(start + lo, P - 1) - U];
    if (xm == t) { *pos_out = start + lo; return true; }
  }
  return false;
}

__global__ void lm_prep(const int* __restrict__ hist, const int* __restrict__ hidx,
                        const int* __restrict__ offsets, const int* __restrict__ ids,
                        const float* __restrict__ logbs,
                        const int* __restrict__ sos_p, const int* __restrict__ N_p,
                        const int* __restrict__ S_p,
                        PerB* __restrict__ pb, int V, int B, int L, int O, int P) {
  int b = blockIdx.x * blockDim.x + threadIdx.x;
  if (b >= B) return;
  int sos = *sos_p, N = *N_p, S = *S_p;
  if (N <= 1) return;
  int shift = (0 <= sos && sos < V) ? 0 : 1;
  int U = V + shift + 1 % N;
  int pad = N - 1;
  int hp = hidx[b] + pad;
  PerB o;
  o.hp = hp;
  for (int k = 0; k < N - 1; ++k) {
    int r = hp - (N - 1) + k;
    int tok = (r < pad) ? sos : hist[(r - pad) * B + b];
    if (shift && tok == sos) tok = V;
    o.ctx[k] = tok;
  }
  o.b1 = logbs[o.ctx[N - 2]];
  int desc = o.ctx[N - 2];
  bool found = true;
  for (int n = 1; n <= N - 2; ++n) {
    int t = o.ctx[(N - 1) - min(n + 1, N - 1)];
    if (found) {
      int pos;
      found = find_child(offsets, ids, desc, t, U, P, S, &pos);
      if (found) desc = pos;
    }
    o.bo[n] = found ? logbs[min(desc, O - 1)] : 0.0f;
  }
  pb[b] = o;
}

__device__ __forceinline__ float score_v(const int* __restrict__ offsets,
                                         const int* __restrict__ ids,
                                         const float* __restrict__ logps,
                                         const PerB* __restrict__ pbb,
                                         int v, float lp0,
                                         int N, int U, int O, int P, int S) {
  float last_lp = lp0;
  float last_bo = pbb->b1;
  int hp = pbb->hp;
  int desc = v;
  bool found = true;
  float cur_lp = lp0;
  for (int n = 1; n <= N - 1; ++n) {
    int t = pbb->ctx[(N - 1) - n];
    if (found) {
      int pos;
      found = find_child(offsets, ids, desc, t, U, P, S, &pos);
      if (found) { desc = pos; cur_lp = logps[desc]; }
    }
    float cur_bo = (n == N - 1) ? 0.0f : pbb->bo[n];
    bool clobber = isfinite(cur_lp) && found;
    float newlp = clobber ? cur_lp : (last_lp + cur_bo + last_bo);
    last_bo = clobber ? cur_bo : 0.0f;
    if (hp >= n) last_lp = newlp;
  }
  return last_lp;
}

__global__ void __launch_bounds__(64)
lm_main2(const int* __restrict__ offsets, const int* __restrict__ ids,
         const float* __restrict__ logps,
         const int* __restrict__ sos_p, const int* __restrict__ N_p,
         const int* __restrict__ S_p,
         const PerB* __restrict__ pb, float* __restrict__ out,
         int V, int B, int O, int P) {
  __shared__ int   s_t1[BG], s_t0[BG], s_hp[BG];
  __shared__ float s_bo1[BG], s_b1[BG];
  __shared__ int   ids_w[64 * WI];
  __shared__ int   off_w[64 * WO];

  const int tid = threadIdx.x;
  const int v   = blockIdx.x * 64 + tid;
  const int b0  = blockIdx.y * BG;
  const int N = *N_p, S = *S_p, sos = *sos_p;
  const int Nc = (N > 0) ? N : 1;
  const int shift = (0 <= sos && sos < V) ? 0 : 1;
  const int U = V + shift + 1 % Nc;

  const bool fast = (N == 3) && (S == 32);

  if (!fast) {
    if (v < V) {
      float lp0 = logps[v];
      if (N <= 1) {
        for (int i = 0; i < BG; ++i) {
          int b = b0 + i;
          if (b < B) out[(size_t)b * V + v] = lp0;
        }
      } else {
        for (int i = 0; i < BG; ++i) {
          int b = b0 + i;
          if (b < B)
            out[(size_t)b * V + v] = score_v(offsets, ids, logps, pb + b, v,
                                             lp0, N, U, O, P, S);
        }
      }
    }
    return;
  }

  if (tid < BG) {
    int b = b0 + tid;
    if (b < B) {
      const PerB* q = pb + b;
      s_t1[tid]  = q->ctx[1];
      s_t0[tid]  = q->ctx[0];
      s_bo1[tid] = q->bo[1];
      s_b1[tid]  = q->b1;
      s_hp[tid]  = q->hp;
    }
  }
  __syncthreads();
  if (v >= V) return;

  const int idsN = P - U;
  float lp0 = logps[v];
  int ov  = offsets[v];
  int ov1 = offsets[v + 1];
  int start1 = ov + v;
  int n1 = ov1 + 1 - ov;
  if (n1 > 32) n1 = 32;

  int* myids = ids_w + tid * WI;
  int* myoff = off_w + tid * WO;
  int aidx0 = start1 - U;
  int sh_i = 0, sh_o = 0;
  bool vec_ok = (start1 >= 0) && (aidx0 >= 0) &&
                (((aidx0 & ~3) + 36) <= idsN) &&
                (((start1 & ~3) + 40) <= O);
  if (vec_ok) {
    int ab = aidx0 & ~3;
    sh_i = aidx0 - ab;
    const int4* ip = (const int4*)(ids + ab);
#pragma unroll
    for (int k = 0; k < 9; ++k) {
      int4 t = ip[k];
      myids[4 * k + 0] = t.x; myids[4 * k + 1] = t.y;
      myids[4 * k + 2] = t.z; myids[4 * k + 3] = t.w;
    }
    int ob = start1 & ~3;
    sh_o = start1 - ob;
    const int4* op = (const int4*)(offsets + ob);
#pragma unroll
    for (int k = 0; k < 10; ++k) {
      int4 t = op[k];
      myoff[4 * k + 0] = t.x; myoff[4 * k + 1] = t.y;
      myoff[4 * k + 2] = t.z; myoff[4 * k + 3] = t.w;
    }
  } else {
    for (int j = 0; j < 36; ++j) {
      int ii = min(start1 + j, P - 1) - U;
      ii = max(0, min(ii, idsN - 1));
      myids[j] = ids[ii];
    }
    for (int j = 0; j < 40; ++j) {
      int oo = max(0, min(start1 + j, O - 1));
      myoff[j] = offsets[oo];
    }
  }
  // each thread reads only its own LDS rows -> no barrier needed

  const int nb = min(BG, B - b0);

  // ---- phase A: LDS-only level-1 resolution + trigram candidate addresses
  int j1v[BG];
  int cc1[BG];
  int cc2[BG];
  unsigned f1m = 0, l2m = 0;
#pragma unroll
  for (int i = 0; i < BG; ++i) {
    if (i >= nb) { j1v[i] = 0; cc1[i] = v; cc2[i] = v; continue; }
    int t1 = s_t1[i];
    bool found = false;
    int j1 = 0;
    if (n1 > 0) {
      int jj = (t1 < n1 - 1) ? t1 : (n1 - 1);
      if (jj < 0) jj = 0;
      int x = myids[sh_i + jj];
      if (x == t1) { found = true; j1 = jj; }
      else if (x > t1) {
        int lo = 0, hi = jj - 1;
        while (lo < hi) {
          int mid = (lo + hi) >> 1;
          if (myids[sh_i + mid] < t1) lo = mid + 1; else hi = mid;
        }
        if (lo < jj && myids[sh_i + lo] == t1) { found = true; j1 = lo; }
      }
    }
    int c1 = start1 + j1;
    j1v[i] = j1;
    int a1 = min(c1, P - 1);
    cc1[i] = a1;
    int t0 = s_t0[i];
    int o1 = myoff[sh_o + j1];
    int o2 = myoff[sh_o + j1 + 1];
    int start2 = o1 + c1;
    int n2 = o2 + 1 - o1;
    if (n2 > 32) n2 = 32;
    bool l2ok = found && (n2 > 0);
    int jj2 = (t0 < n2 - 1) ? t0 : (n2 - 1);
    if (jj2 < 0) jj2 = 0;
    int c2 = min(start2 + jj2, P - 1);
    cc2[i] = l2ok ? c2 : a1;   // aliases an already-fetched line when skipped
    f1m |= (found ? 1u : 0u) << i;
    l2m |= (l2ok ? 1u : 0u) << i;
  }

  // ---- phase B: batched global loads, no branches in between.
  // Bigram logps lines are shared across b within this v -> normal loads.
  // Trigram probe lines are use-once -> non-temporal (don't evict the
  // reused bigram window working set from L2).
  float lp1v[BG];
  int   x2v[BG];
  float sp2v[BG];
#pragma unroll
  for (int i = 0; i < BG; ++i) lp1v[i] = logps[cc1[i]];
#pragma unroll
  for (int i = 0; i < BG; ++i) {
    int ii = cc2[i] - U;
    ii = max(0, min(ii, idsN - 1));
    x2v[i] = __builtin_nontemporal_load(ids + ii);
  }
#pragma unroll
  for (int i = 0; i < BG; ++i)
    sp2v[i] = __builtin_nontemporal_load(logps + cc2[i]);

  // ---- phase C: finalize (pure ALU; global search fallback is cold)
#pragma unroll
  for (int i = 0; i < BG; ++i) {
    if (i >= nb) continue;
    bool found = (f1m >> i) & 1u;
    bool l2ok  = (l2m >> i) & 1u;
    int   hp = s_hp[i];
    float bo1 = s_bo1[i];
    float last_bo = s_b1[i];
    float last_lp = lp0;

    float lp1 = found ? lp1v[i] : lp0;
    bool clob = found && isfinite(lp1);
    float nl = clob ? lp1 : (last_lp + bo1 + last_bo);
    last_bo = clob ? bo1 : 0.0f;
    if (hp >= 1) last_lp = nl;

    bool f2 = false;
    float lp2 = 0.0f;
    if (l2ok) {
      int t0 = s_t0[i];
      int x2 = x2v[i];
      if (x2 == t0) { f2 = true; lp2 = sp2v[i]; }
      else if (x2 > t0) {
        // cold: sorted-window binary search in global ids
        int j1 = j1v[i];
        int c1 = start1 + j1;
        int o1 = myoff[sh_o + j1];
        int o2 = myoff[sh_o + j1 + 1];
        int start2 = o1 + c1;
        int n2 = o2 + 1 - o1;
        if (n2 > 32) n2 = 32;
        int jj2 = (t0 < n2 - 1) ? t0 : (n2 - 1);
        if (jj2 < 0) jj2 = 0;
        int lo = 0, hi = jj2 - 1;
        while (lo < hi) {
          int mid = (lo + hi) >> 1;
          int im = max(0, min(min(start2 + mid, P - 1) - U, idsN - 1));
          if (ids[im] < t0) lo = mid + 1; else hi = mid;
        }
        if (lo < jj2) {
          int il = max(0, min(min(start2 + lo, P - 1) - U, idsN - 1));
          if (ids[il] == t0) { f2 = true; lp2 = logps[min(start2 + lo, P - 1)]; }
        }
      }
    }
    bool clob2 = f2 && isfinite(lp2);
    float nl2 = clob2 ? lp2 : (last_lp + last_bo);
    if (hp >= 2) last_lp = nl2;

    __builtin_nontemporal_store(last_lp, out + (size_t)(b0 + i) * V + v);
  }
}

extern "C" void kernel_launch(void* const* d_in, const int* in_sizes, int n_in,
                              void* d_out, int out_size, void* d_ws, size_t ws_size,
                              hipStream_t stream) {
  const int*   hist    = (const int*)d_in[0];
  const int*   hidx    = (const int*)d_in[1];
  const int*   offsets = (const int*)d_in[2];
  const int*   ids     = (const int*)d_in[3];
  const float* logps   = (const float*)d_in[4];
  const float* logbs   = (const float*)d_in[5];
  const int*   sos_p   = (const int*)d_in[6];
  const int*   N_p     = (const int*)d_in[8];
  const int*   S_p     = (const int*)d_in[10];

  int B = in_sizes[1];
  int L = in_sizes[0] / B;
  int O = in_sizes[2];
  int P = in_sizes[4];
  int V = out_size / B;
  float* out = (float*)d_out;
  PerB* pb = (PerB*)d_ws;

  lm_prep<<<dim3((B + 63) / 64), dim3(64), 0, stream>>>(
      hist, hidx, offsets, ids, logbs, sos_p, N_p, S_p, pb, V, B, L, O, P);

  dim3 grid((V + 63) / 64, (B + BG - 1) / BG);
  lm_main2<<<grid, dim3(64), 0, stream>>>(
      offsets, ids, logps, sos_p, N_p, S_p, pb, out, V, B, O, P);
}

// Round 6
// 271.328 us; speedup vs baseline: 1.0355x; 1.0152x over previous
//
#include <hip/hip_runtime.h>
#include <math.h>

// LookupLanguageModel: n-gram backoff LM over a CSR-flattened trie.
// R6: one 256-thread block (4 waves) owns 64 v's for ALL 32 batches.
// The per-v child-id/child-offset windows are staged cooperatively ONCE
// (4 threads per row, int4 slices) into LDS; each wave then resolves 8
// batches from the shared windows. vs R5: staging traffic/instructions
// halve AND wave count doubles (1000 -> 2000 waves, ~2 waves/SIMD).
// Trigram probes + output stores stay non-temporal (use-once lines).

#define MAXN 8
#define BGW  8    // batches per wave
#define BGB  32   // batches per block (4 waves)
#define WI   37   // LDS row stride for ids window (odd => conflict-free)
#define WO   41   // LDS row stride for offsets window (odd)

struct PerB {
  int   ctx[MAXN];
  float bo[MAXN];
  float b1;
  int   hp;
};

__device__ __forceinline__ bool find_child(const int* __restrict__ offsets,
                                           const int* __restrict__ ids,
                                           int q, int t, int U, int P, int S,
                                           int* pos_out) {
  int start = offsets[q] + q;
  int end   = offsets[q + 1] + q + 1;
  int n = end - start;
  if (n > S) n = S;
  if (n <= 0) return false;
  int j = (t < n - 1) ? t : (n - 1);
  if (j < 0) j = 0;
  int x = ids[min(start + j, P - 1) - U];
  if (x == t) { *pos_out = start + j; return true; }
  if (x < t) return false;
  int lo = 0, hi = j - 1;
  while (lo < hi) {
    int mid = (lo + hi) >> 1;
    int xm = ids[min(start + mid, P - 1) - U];
    if (xm < t) lo = mid + 1; else hi = mid;
  }
  if (lo < j) {
    int xm = ids[min(start + lo, P - 1) - U];
    if (xm == t) { *pos_out = start + lo; return true; }
  }
  return false;
}

__global__ void lm_prep(const int* __restrict__ hist, const int* __restrict__ hidx,
                        const int* __restrict__ offsets, const int* __restrict__ ids,
                        const float* __restrict__ logbs,
                        const int* __restrict__ sos_p, const int* __restrict__ N_p,
                        const int* __restrict__ S_p,
                        PerB* __restrict__ pb, int V, int B, int L, int O, int P) {
  int b = blockIdx.x * blockDim.x + threadIdx.x;
  if (b >= B) return;
  int sos = *sos_p, N = *N_p, S = *S_p;
  if (N <= 1) return;
  int shift = (0 <= sos && sos < V) ? 0 : 1;
  int U = V + shift + 1 % N;
  int pad = N - 1;
  int hp = hidx[b] + pad;
  PerB o;
  o.hp = hp;
  for (int k = 0; k < N - 1; ++k) {
    int r = hp - (N - 1) + k;
    int tok = (r < pad) ? sos : hist[(r - pad) * B + b];
    if (shift && tok == sos) tok = V;
    o.ctx[k] = tok;
  }
  o.b1 = logbs[o.ctx[N - 2]];
  int desc = o.ctx[N - 2];
  bool found = true;
  for (int n = 1; n <= N - 2; ++n) {
    int t = o.ctx[(N - 1) - min(n + 1, N - 1)];
    if (found) {
      int pos;
      found = find_child(offsets, ids, desc, t, U, P, S, &pos);
      if (found) desc = pos;
    }
    o.bo[n] = found ? logbs[min(desc, O - 1)] : 0.0f;
  }
  pb[b] = o;
}

__device__ __forceinline__ float score_v(const int* __restrict__ offsets,
                                         const int* __restrict__ ids,
                                         const float* __restrict__ logps,
                                         const PerB* __restrict__ pbb,
                                         int v, float lp0,
                                         int N, int U, int O, int P, int S) {
  float last_lp = lp0;
  float last_bo = pbb->b1;
  int hp = pbb->hp;
  int desc = v;
  bool found = true;
  float cur_lp = lp0;
  for (int n = 1; n <= N - 1; ++n) {
    int t = pbb->ctx[(N - 1) - n];
    if (found) {
      int pos;
      found = find_child(offsets, ids, desc, t, U, P, S, &pos);
      if (found) { desc = pos; cur_lp = logps[desc]; }
    }
    float cur_bo = (n == N - 1) ? 0.0f : pbb->bo[n];
    bool clobber = isfinite(cur_lp) && found;
    float newlp = clobber ? cur_lp : (last_lp + cur_bo + last_bo);
    last_bo = clobber ? cur_bo : 0.0f;
    if (hp >= n) last_lp = newlp;
  }
  return last_lp;
}

__global__ void __launch_bounds__(256)
lm_main3(const int* __restrict__ offsets, const int* __restrict__ ids,
         const float* __restrict__ logps,
         const int* __restrict__ sos_p, const int* __restrict__ N_p,
         const int* __restrict__ S_p,
         const PerB* __restrict__ pb, float* __restrict__ out,
         int V, int B, int O, int P) {
  __shared__ int   s_t1[BGB], s_t0[BGB], s_hp[BGB];
  __shared__ float s_bo1[BGB], s_b1[BGB];
  __shared__ int   ids_w[64 * WI];
  __shared__ int   off_w[64 * WO];
  __shared__ int   s_start1[64], s_n1[64], s_shi[64], s_sho[64];

  const int tid  = threadIdx.x;
  const int lane = tid & 63;
  const int w    = tid >> 6;
  const int vbase = blockIdx.x * 64;
  const int v     = vbase + lane;
  const int b0    = blockIdx.y * BGB;
  const int N = *N_p, S = *S_p, sos = *sos_p;
  const int Nc = (N > 0) ? N : 1;
  const int shift = (0 <= sos && sos < V) ? 0 : 1;
  const int U = V + shift + 1 % Nc;

  const bool fast = (N == 3) && (S == 32);

  if (!fast) {
    if (v < V) {
      float lp0 = logps[v];
      if (N <= 1) {
        for (int ib = w; ib < BGB; ib += 4) {
          int b = b0 + ib;
          if (b < B) out[(size_t)b * V + v] = lp0;
        }
      } else {
        for (int ib = w; ib < BGB; ib += 4) {
          int b = b0 + ib;
          if (b < B)
            out[(size_t)b * V + v] = score_v(offsets, ids, logps, pb + b, v,
                                             lp0, N, U, O, P, S);
        }
      }
    }
    return;
  }

  // per-batch state into LDS
  if (tid < BGB) {
    int b = b0 + tid;
    if (b < B) {
      const PerB* q = pb + b;
      s_t1[tid]  = q->ctx[1];
      s_t0[tid]  = q->ctx[0];
      s_bo1[tid] = q->bo[1];
      s_b1[tid]  = q->b1;
      s_hp[tid]  = q->hp;
    }
  }

  const int idsN = P - U;

  // cooperative window staging: 4 threads per row, once per v for ALL batches
  {
    int row  = tid >> 2;
    int part = tid & 3;
    int vv = vbase + row;
    if (vv < V) {
      int ov  = offsets[vv];
      int ov1 = offsets[vv + 1];
      int start1 = ov + vv;
      int n1 = ov1 + 1 - ov;
      if (n1 > 32) n1 = 32;
      int* myids = ids_w + row * WI;
      int* myoff = off_w + row * WO;
      int aidx0 = start1 - U;
      int sh_i = 0, sh_o = 0;
      bool vec_ok = (start1 >= 0) && (aidx0 >= 0) &&
                    (((aidx0 & ~3) + 36) <= idsN) &&
                    (((start1 & ~3) + 40) <= O);
      if (vec_ok) {
        int ab = aidx0 & ~3;
        sh_i = aidx0 - ab;
        const int4* ip = (const int4*)(ids + ab);
        for (int k = part; k < 9; k += 4) {
          int4 t = ip[k];
          myids[4 * k + 0] = t.x; myids[4 * k + 1] = t.y;
          myids[4 * k + 2] = t.z; myids[4 * k + 3] = t.w;
        }
        int ob = start1 & ~3;
        sh_o = start1 - ob;
        const int4* op = (const int4*)(offsets + ob);
        for (int k = part; k < 10; k += 4) {
          int4 t = op[k];
          myoff[4 * k + 0] = t.x; myoff[4 * k + 1] = t.y;
          myoff[4 * k + 2] = t.z; myoff[4 * k + 3] = t.w;
        }
      } else {
        for (int j = part; j < 36; j += 4) {
          int ii = min(start1 + j, P - 1) - U;
          ii = max(0, min(ii, idsN - 1));
          myids[j] = ids[ii];
        }
        for (int j = part; j < 40; j += 4) {
          int oo = max(0, min(start1 + j, O - 1));
          myoff[j] = offsets[oo];
        }
      }
      if (part == 0) {
        s_start1[row] = start1; s_n1[row] = n1;
        s_shi[row] = sh_i;      s_sho[row] = sh_o;
      }
    } else if (part == 0) {
      s_start1[row] = 0; s_n1[row] = 0; s_shi[row] = 0; s_sho[row] = 0;
    }
  }
  __syncthreads();
  if (v >= V) return;

  float lp0 = logps[v];
  const int start1 = s_start1[lane];
  const int n1     = s_n1[lane];
  const int sh_i   = s_shi[lane];
  const int sh_o   = s_sho[lane];
  const int* myids = ids_w + lane * WI;
  const int* myoff = off_w + lane * WO;

  const int nb = min(BGB, B - b0);

  // ---- phase A: LDS-only level-1 resolution + trigram candidate addresses
  int j1v[BGW];
  int cc1[BGW];
  int cc2[BGW];
  unsigned f1m = 0, l2m = 0;
#pragma unroll
  for (int i = 0; i < BGW; ++i) {
    int ib = w * BGW + i;
    if (ib >= nb) { j1v[i] = 0; cc1[i] = v; cc2[i] = v; continue; }
    int t1 = s_t1[ib];
    bool found = false;
    int j1 = 0;
    if (n1 > 0) {
      int jj = (t1 < n1 - 1) ? t1 : (n1 - 1);
      if (jj < 0) jj = 0;
      int x = myids[sh_i + jj];
      if (x == t1) { found = true; j1 = jj; }
      else if (x > t1) {
        int lo = 0, hi = jj - 1;
        while (lo < hi) {
          int mid = (lo + hi) >> 1;
          if (myids[sh_i + mid] < t1) lo = mid + 1; else hi = mid;
        }
        if (lo < jj && myids[sh_i + lo] == t1) { found = true; j1 = lo; }
      }
    }
    int c1 = start1 + j1;
    j1v[i] = j1;
    int a1 = min(c1, P - 1);
    cc1[i] = a1;
    int t0 = s_t0[ib];
    int o1 = myoff[sh_o + j1];
    int o2 = myoff[sh_o + j1 + 1];
    int start2 = o1 + c1;
    int n2 = o2 + 1 - o1;
    if (n2 > 32) n2 = 32;
    bool l2ok = found && (n2 > 0);
    int jj2 = (t0 < n2 - 1) ? t0 : (n2 - 1);
    if (jj2 < 0) jj2 = 0;
    int c2 = min(start2 + jj2, P - 1);
    cc2[i] = l2ok ? c2 : a1;   // aliases an already-fetched line when skipped
    f1m |= (found ? 1u : 0u) << i;
    l2m |= (l2ok ? 1u : 0u) << i;
  }

  // ---- phase B: batched global loads, no branches in between
  float lp1v[BGW];
  int   x2v[BGW];
  float sp2v[BGW];
#pragma unroll
  for (int i = 0; i < BGW; ++i) lp1v[i] = logps[cc1[i]];
#pragma unroll
  for (int i = 0; i < BGW; ++i) {
    int ii = cc2[i] - U;
    ii = max(0, min(ii, idsN - 1));
    x2v[i] = __builtin_nontemporal_load(ids + ii);
  }
#pragma unroll
  for (int i = 0; i < BGW; ++i)
    sp2v[i] = __builtin_nontemporal_load(logps + cc2[i]);

  // ---- phase C: finalize (pure ALU; global search fallback is cold)
#pragma unroll
  for (int i = 0; i < BGW; ++i) {
    int ib = w * BGW + i;
    if (ib >= nb) continue;
    bool found = (f1m >> i) & 1u;
    bool l2ok  = (l2m >> i) & 1u;
    int   hp = s_hp[ib];
    float bo1 = s_bo1[ib];
    float last_bo = s_b1[ib];
    float last_lp = lp0;

    float lp1 = found ? lp1v[i] : lp0;
    bool clob = found && isfinite(lp1);
    float nl = clob ? lp1 : (last_lp + bo1 + last_bo);
    last_bo = clob ? bo1 : 0.0f;
    if (hp >= 1) last_lp = nl;

    bool f2 = false;
    float lp2 = 0.0f;
    if (l2ok) {
      int t0 = s_t0[ib];
      int x2 = x2v[i];
      if (x2 == t0) { f2 = true; lp2 = sp2v[i]; }
      else if (x2 > t0) {
        // cold: sorted-window binary search in global ids
        int j1 = j1v[i];
        int c1 = start1 + j1;
        int o1 = myoff[sh_o + j1];
        int o2 = myoff[sh_o + j1 + 1];
        int start2 = o1 + c1;
        int n2 = o2 + 1 - o1;
        if (n2 > 32) n2 = 32;
        int jj2 = (t0 < n2 - 1) ? t0 : (n2 - 1);
        if (jj2 < 0) jj2 = 0;
        int lo = 0, hi = jj2 - 1;
        while (lo < hi) {
          int mid = (lo + hi) >> 1;
          int im = max(0, min(min(start2 + mid, P - 1) - U, idsN - 1));
          if (ids[im] < t0) lo = mid + 1; else hi = mid;
        }
        if (lo < jj2) {
          int il = max(0, min(min(start2 + lo, P - 1) - U, idsN - 1));
          if (ids[il] == t0) { f2 = true; lp2 = logps[min(start2 + lo, P - 1)]; }
        }
      }
    }
    bool clob2 = f2 && isfinite(lp2);
    float nl2 = clob2 ? lp2 : (last_lp + last_bo);
    if (hp >= 2) last_lp = nl2;

    __builtin_nontemporal_store(last_lp, out + (size_t)(b0 + ib) * V + v);
  }
}

extern "C" void kernel_launch(void* const* d_in, const int* in_sizes, int n_in,
                              void* d_out, int out_size, void* d_ws, size_t ws_size,
                              hipStream_t stream) {
  const int*   hist    = (const int*)d_in[0];
  const int*   hidx    = (const int*)d_in[1];
  const int*   offsets = (const int*)d_in[2];
  const int*   ids     = (const int*)d_in[3];
  const float* logps   = (const float*)d_in[4];
  const float* logbs   = (const float*)d_in[5];
  const int*   sos_p   = (const int*)d_in[6];
  const int*   N_p     = (const int*)d_in[8];
  const int*   S_p     = (const int*)d_in[10];

  int B = in_sizes[1];
  int L = in_sizes[0] / B;
  int O = in_sizes[2];
  int P = in_sizes[4];
  int V = out_size / B;
  float* out = (float*)d_out;
  PerB* pb = (PerB*)d_ws;

  lm_prep<<<dim3((B + 63) / 64), dim3(64), 0, stream>>>(
      hist, hidx, offsets, ids, logbs, sos_p, N_p, S_p, pb, V, B, L, O, P);

  dim3 grid((V + 63) / 64, (B + BGB - 1) / BGB);
  lm_main3<<<grid, dim3(256), 0, stream>>>(
      offsets, ids, logps, sos_p, N_p, S_p, pb, out, V, B, O, P);
}

// Round 7
// 269.389 us; speedup vs baseline: 1.0429x; 1.0072x over previous
//
#include <hip/hip_runtime.h>
#include <math.h>

// LookupLanguageModel: n-gram backoff LM over a CSR-flattened trie.
// R7: single fused kernel. Each 256-thread block (4 waves) owns 64 v's for
// all 32 batches. Threads 0..31 compute the per-batch context chain (prep)
// directly into LDS while the remaining threads cooperatively stage the
// per-v child-id/child-offset windows (int4, 4 threads/row); one barrier,
// then each wave resolves 8 batches from LDS. Trigram probes + output
// stores are non-temporal (use-once lines). No lm_prep launch, no d_ws.

#define MAXN 8
#define BGW  8    // batches per wave
#define BGB  32   // batches per block (4 waves)
#define WI   37   // LDS row stride for ids window (odd => conflict-free)
#define WO   41   // LDS row stride for offsets window (odd)

struct PerB {
  int   ctx[MAXN];
  float bo[MAXN];
  float b1;
  int   hp;
};

__device__ __forceinline__ bool find_child(const int* __restrict__ offsets,
                                           const int* __restrict__ ids,
                                           int q, int t, int U, int P, int S,
                                           int* pos_out) {
  int start = offsets[q] + q;
  int end   = offsets[q + 1] + q + 1;
  int n = end - start;
  if (n > S) n = S;
  if (n <= 0) return false;
  int j = (t < n - 1) ? t : (n - 1);
  if (j < 0) j = 0;
  int x = ids[min(start + j, P - 1) - U];
  if (x == t) { *pos_out = start + j; return true; }
  if (x < t) return false;
  int lo = 0, hi = j - 1;
  while (lo < hi) {
    int mid = (lo + hi) >> 1;
    int xm = ids[min(start + mid, P - 1) - U];
    if (xm < t) lo = mid + 1; else hi = mid;
  }
  if (lo < j) {
    int xm = ids[min(start + lo, P - 1) - U];
    if (xm == t) { *pos_out = start + lo; return true; }
  }
  return false;
}

__device__ __forceinline__ float score_v(const int* __restrict__ offsets,
                                         const int* __restrict__ ids,
                                         const float* __restrict__ logps,
                                         const PerB* __restrict__ pbb,
                                         int v, float lp0,
                                         int N, int U, int O, int P, int S) {
  float last_lp = lp0;
  float last_bo = pbb->b1;
  int hp = pbb->hp;
  int desc = v;
  bool found = true;
  float cur_lp = lp0;
  for (int n = 1; n <= N - 1; ++n) {
    int t = pbb->ctx[(N - 1) - n];
    if (found) {
      int pos;
      found = find_child(offsets, ids, desc, t, U, P, S, &pos);
      if (found) { desc = pos; cur_lp = logps[desc]; }
    }
    float cur_bo = (n == N - 1) ? 0.0f : pbb->bo[n];
    bool clobber = isfinite(cur_lp) && found;
    float newlp = clobber ? cur_lp : (last_lp + cur_bo + last_bo);
    last_bo = clobber ? cur_bo : 0.0f;
    if (hp >= n) last_lp = newlp;
  }
  return last_lp;
}

__global__ void __launch_bounds__(256)
lm_fused(const int* __restrict__ hist, const int* __restrict__ hidx,
         const int* __restrict__ offsets, const int* __restrict__ ids,
         const float* __restrict__ logps, const float* __restrict__ logbs,
         const int* __restrict__ sos_p, const int* __restrict__ N_p,
         const int* __restrict__ S_p,
         float* __restrict__ out,
         int V, int B, int L, int O, int P) {
  __shared__ PerB s_pb[BGB];
  __shared__ int  ids_w[64 * WI];
  __shared__ int  off_w[64 * WO];
  __shared__ int  s_start1[64], s_n1[64], s_shi[64], s_sho[64];

  const int tid  = threadIdx.x;
  const int lane = tid & 63;
  const int w    = tid >> 6;
  const int vbase = blockIdx.x * 64;
  const int v     = vbase + lane;
  const int b0    = blockIdx.y * BGB;
  const int N = *N_p, S = *S_p, sos = *sos_p;
  const int Nc = (N > 0) ? N : 1;
  const int shift = (0 <= sos && sos < V) ? 0 : 1;
  const int U = V + shift + 1 % Nc;
  const int idsN = P - U;

  const bool fast = (N == 3) && (S == 32);

  // ---- inline prep: threads 0..BGB-1 compute per-batch context chain
  if (tid < BGB && N > 1) {
    int b = b0 + tid;
    if (b < B) {
      int pad = N - 1;
      int hp = hidx[b] + pad;
      PerB o;
      o.hp = hp;
      for (int k = 0; k < N - 1; ++k) {
        int r = hp - (N - 1) + k;
        int tok = (r < pad) ? sos : hist[(r - pad) * B + b];
        if (shift && tok == sos) tok = V;
        o.ctx[k] = tok;
      }
      o.b1 = logbs[o.ctx[N - 2]];
      int desc = o.ctx[N - 2];
      bool found = true;
      for (int n = 1; n <= N - 2; ++n) {
        int t = o.ctx[(N - 1) - min(n + 1, N - 1)];
        if (found) {
          int pos;
          found = find_child(offsets, ids, desc, t, U, P, S, &pos);
          if (found) desc = pos;
        }
        o.bo[n] = found ? logbs[min(desc, O - 1)] : 0.0f;
      }
      s_pb[tid] = o;
    }
  }

  if (!fast) {
    __syncthreads();
    if (v < V) {
      float lp0 = logps[v];
      if (N <= 1) {
        for (int ib = w; ib < BGB; ib += 4) {
          int b = b0 + ib;
          if (b < B) out[(size_t)b * V + v] = lp0;
        }
      } else {
        for (int ib = w; ib < BGB; ib += 4) {
          int b = b0 + ib;
          if (b < B)
            out[(size_t)b * V + v] = score_v(offsets, ids, logps, s_pb + ib, v,
                                             lp0, N, U, O, P, S);
        }
      }
    }
    return;
  }

  // ---- cooperative window staging: 4 threads per row, once per v
  {
    int row  = tid >> 2;
    int part = tid & 3;
    int vv = vbase + row;
    if (vv < V) {
      int ov  = offsets[vv];
      int ov1 = offsets[vv + 1];
      int start1 = ov + vv;
      int n1 = ov1 + 1 - ov;
      if (n1 > 32) n1 = 32;
      int* myids = ids_w + row * WI;
      int* myoff = off_w + row * WO;
      int aidx0 = start1 - U;
      int sh_i = 0, sh_o = 0;
      bool vec_ok = (start1 >= 0) && (aidx0 >= 0) &&
                    (((aidx0 & ~3) + 36) <= idsN) &&
                    (((start1 & ~3) + 40) <= O);
      if (vec_ok) {
        int ab = aidx0 & ~3;
        sh_i = aidx0 - ab;
        const int4* ip = (const int4*)(ids + ab);
        for (int k = part; k < 9; k += 4) {
          int4 t = ip[k];
          myids[4 * k + 0] = t.x; myids[4 * k + 1] = t.y;
          myids[4 * k + 2] = t.z; myids[4 * k + 3] = t.w;
        }
        int ob = start1 & ~3;
        sh_o = start1 - ob;
        const int4* op = (const int4*)(offsets + ob);
        for (int k = part; k < 10; k += 4) {
          int4 t = op[k];
          myoff[4 * k + 0] = t.x; myoff[4 * k + 1] = t.y;
          myoff[4 * k + 2] = t.z; myoff[4 * k + 3] = t.w;
        }
      } else {
        for (int j = part; j < 36; j += 4) {
          int ii = min(start1 + j, P - 1) - U;
          ii = max(0, min(ii, idsN - 1));
          myids[j] = ids[ii];
        }
        for (int j = part; j < 40; j += 4) {
          int oo = max(0, min(start1 + j, O - 1));
          myoff[j] = offsets[oo];
        }
      }
      if (part == 0) {
        s_start1[row] = start1; s_n1[row] = n1;
        s_shi[row] = sh_i;      s_sho[row] = sh_o;
      }
    } else if (part == 0) {
      s_start1[row] = 0; s_n1[row] = 0; s_shi[row] = 0; s_sho[row] = 0;
    }
  }
  __syncthreads();
  if (v >= V) return;

  float lp0 = logps[v];
  const int start1 = s_start1[lane];
  const int n1     = s_n1[lane];
  const int sh_i   = s_shi[lane];
  const int sh_o   = s_sho[lane];
  const int* myids = ids_w + lane * WI;
  const int* myoff = off_w + lane * WO;

  const int nb = min(BGB, B - b0);

  // ---- phase A: LDS-only level-1 resolution + trigram candidate addresses
  int j1v[BGW];
  int cc1[BGW];
  int cc2[BGW];
  unsigned f1m = 0, l2m = 0;
#pragma unroll
  for (int i = 0; i < BGW; ++i) {
    int ib = w * BGW + i;
    if (ib >= nb) { j1v[i] = 0; cc1[i] = v; cc2[i] = v; continue; }
    int t1 = s_pb[ib].ctx[1];
    bool found = false;
    int j1 = 0;
    if (n1 > 0) {
      int jj = (t1 < n1 - 1) ? t1 : (n1 - 1);
      if (jj < 0) jj = 0;
      int x = myids[sh_i + jj];
      if (x == t1) { found = true; j1 = jj; }
      else if (x > t1) {
        int lo = 0, hi = jj - 1;
        while (lo < hi) {
          int mid = (lo + hi) >> 1;
          if (myids[sh_i + mid] < t1) lo = mid + 1; else hi = mid;
        }
        if (lo < jj && myids[sh_i + lo] == t1) { found = true; j1 = lo; }
      }
    }
    int c1 = start1 + j1;
    j1v[i] = j1;
    int a1 = min(c1, P - 1);
    cc1[i] = a1;
    int t0 = s_pb[ib].ctx[0];
    int o1 = myoff[sh_o + j1];
    int o2 = myoff[sh_o + j1 + 1];
    int start2 = o1 + c1;
    int n2 = o2 + 1 - o1;
    if (n2 > 32) n2 = 32;
    bool l2ok = found && (n2 > 0);
    int jj2 = (t0 < n2 - 1) ? t0 : (n2 - 1);
    if (jj2 < 0) jj2 = 0;
    int c2 = min(start2 + jj2, P - 1);
    cc2[i] = l2ok ? c2 : a1;   // aliases an already-fetched line when skipped
    f1m |= (found ? 1u : 0u) << i;
    l2m |= (l2ok ? 1u : 0u) << i;
  }

  // ---- phase B: batched global loads, no branches in between
  float lp1v[BGW];
  int   x2v[BGW];
  float sp2v[BGW];
#pragma unroll
  for (int i = 0; i < BGW; ++i) lp1v[i] = logps[cc1[i]];
#pragma unroll
  for (int i = 0; i < BGW; ++i) {
    int ii = cc2[i] - U;
    ii = max(0, min(ii, idsN - 1));
    x2v[i] = __builtin_nontemporal_load(ids + ii);
  }
#pragma unroll
  for (int i = 0; i < BGW; ++i)
    sp2v[i] = __builtin_nontemporal_load(logps + cc2[i]);

  // ---- phase C: finalize (pure ALU; global search fallback is cold)
#pragma unroll
  for (int i = 0; i < BGW; ++i) {
    int ib = w * BGW + i;
    if (ib >= nb) continue;
    bool found = (f1m >> i) & 1u;
    bool l2ok  = (l2m >> i) & 1u;
    int   hp = s_pb[ib].hp;
    float bo1 = s_pb[ib].bo[1];
    float last_bo = s_pb[ib].b1;
    float last_lp = lp0;

    float lp1 = found ? lp1v[i] : lp0;
    bool clob = found && isfinite(lp1);
    float nl = clob ? lp1 : (last_lp + bo1 + last_bo);
    last_bo = clob ? bo1 : 0.0f;
    if (hp >= 1) last_lp = nl;

    bool f2 = false;
    float lp2 = 0.0f;
    if (l2ok) {
      int t0 = s_pb[ib].ctx[0];
      int x2 = x2v[i];
      if (x2 == t0) { f2 = true; lp2 = sp2v[i]; }
      else if (x2 > t0) {
        // cold: sorted-window binary search in global ids
        int j1 = j1v[i];
        int c1 = start1 + j1;
        int o1 = myoff[sh_o + j1];
        int o2 = myoff[sh_o + j1 + 1];
        int start2 = o1 + c1;
        int n2 = o2 + 1 - o1;
        if (n2 > 32) n2 = 32;
        int jj2 = (t0 < n2 - 1) ? t0 : (n2 - 1);
        if (jj2 < 0) jj2 = 0;
        int lo = 0, hi = jj2 - 1;
        while (lo < hi) {
          int mid = (lo + hi) >> 1;
          int im = max(0, min(min(start2 + mid, P - 1) - U, idsN - 1));
          if (ids[im] < t0) lo = mid + 1; else hi = mid;
        }
        if (lo < jj2) {
          int il = max(0, min(min(start2 + lo, P - 1) - U, idsN - 1));
          if (ids[il] == t0) { f2 = true; lp2 = logps[min(start2 + lo, P - 1)]; }
        }
      }
    }
    bool clob2 = f2 && isfinite(lp2);
    float nl2 = clob2 ? lp2 : (last_lp + last_bo);
    if (hp >= 2) last_lp = nl2;

    __builtin_nontemporal_store(last_lp, out + (size_t)(b0 + ib) * V + v);
  }
}

extern "C" void kernel_launch(void* const* d_in, const int* in_sizes, int n_in,
                              void* d_out, int out_size, void* d_ws, size_t ws_size,
                              hipStream_t stream) {
  const int*   hist    = (const int*)d_in[0];
  const int*   hidx    = (const int*)d_in[1];
  const int*   offsets = (const int*)d_in[2];
  const int*   ids     = (const int*)d_in[3];
  const float* logps   = (const float*)d_in[4];
  const float* logbs   = (const float*)d_in[5];
  const int*   sos_p   = (const int*)d_in[6];
  const int*   N_p     = (const int*)d_in[8];
  const int*   S_p     = (const int*)d_in[10];

  int B = in_sizes[1];
  int L = in_sizes[0] / B;
  int O = in_sizes[2];
  int P = in_sizes[4];
  int V = out_size / B;
  float* out = (float*)d_out;

  dim3 grid((V + 63) / 64, (B + BGB - 1) / BGB);
  lm_fused<<<grid, dim3(256), 0, stream>>>(
      hist, hidx, offsets, ids, logps, logbs, sos_p, N_p, S_p, out,
      V, B, L, O, P);
}